// Round 6
// baseline (1217.047 us; speedup 1.0000x reference)
//
#include <hip/hip_runtime.h>

#define S_LEN 2048
#define NHEADS 16
#define DK 64
#define DMODEL 1024
#define QSCALE 0.18033688011f  /* 0.125 * log2(e) */

typedef float f32x4 __attribute__((ext_vector_type(4)));
typedef _Float16 f16x8 __attribute__((ext_vector_type(8)));
typedef _Float16 f16x4 __attribute__((ext_vector_type(4)));
typedef __fp16 h16x2 __attribute__((ext_vector_type(2)));   // cvt_pkrtz native type

__device__ __forceinline__ unsigned short f2h_bits(float f) {
  _Float16 h = (_Float16)f;
  unsigned short u; __builtin_memcpy(&u, &h, 2); return u;
}

__device__ __forceinline__ f32x4 mfma16(f16x8 a, f16x8 b, f32x4 c) {
  return __builtin_amdgcn_mfma_f32_16x16x32_f16(a, b, c, 0, 0, 0);
}
__device__ __forceinline__ f16x8 frag_ld(const unsigned short* p) {
  return *(const f16x8*)p;
}

#define GLD_LDS(g, l)                                                          \
  __builtin_amdgcn_global_load_lds(                                            \
      (const __attribute__((address_space(1))) void*)(g),                      \
      (__attribute__((address_space(3))) void*)(l), 16, 0, 0)

// ---------------- fp32 -> fp16 convert (contiguous) ----------------
__global__ void convert_f32_f16(const float* __restrict__ in,
                                unsigned short* __restrict__ out, int n4) {
  int i = blockIdx.x * blockDim.x + threadIdx.x;
  if (i < n4) {
    f32x4 v = *(const f32x4*)(in + (size_t)i * 4);
    unsigned short o[4];
#pragma unroll
    for (int j = 0; j < 4; j++) o[j] = f2h_bits(v[j]);
    *(uint2*)(out + (size_t)i * 4) = *(const uint2*)o;
  }
}

// ---------------- fp32 -> fp16 transpose ----------------
__global__ void transpose_f32_f16(const float* __restrict__ in,
                                  unsigned short* __restrict__ out, int R, int C) {
  __shared__ unsigned short tile[32][33];
  int bx = blockIdx.x * 32, by = blockIdx.y * 32;
  int tx = threadIdx.x, ty = threadIdx.y;
  for (int i = ty; i < 32; i += 8)
    tile[i][tx] = f2h_bits(in[(size_t)(by + i) * C + bx + tx]);
  __syncthreads();
  for (int i = ty; i < 32; i += 8)
    out[(size_t)(bx + i) * R + by + tx] = tile[tx][i];
}

// ---------------- 128x128 MFMA GEMM, B^T input (m97 structure), fp16 in fp32 acc
// + T1 bijective XCD-chunked block swizzle.
// Epilogue writes attn-fragment-native layouts so attn loads K/V frags DIRECTLY
// from global, fully coalesced (no LDS, no barriers there):
//   K: [bh][jblk=s>>5][khalf=d>>5][s&31][d&31]
//   V: [bh][pblk=s>>5][d][p]  with within-32 j-permutation p = 8g+4jsub+r
//      (from s&31 = 16jsub+4g+r) so PV B-frags are contiguous 16B.
__launch_bounds__(256)
__global__ void gemm_bt(const unsigned short* __restrict__ A,
                        const unsigned short* __restrict__ Bt,
                        int M, int N, int K, int mode,
                        const float* __restrict__ bias,
                        float* __restrict__ out0,
                        unsigned short* __restrict__ q_o,
                        unsigned short* __restrict__ k_o,
                        unsigned short* __restrict__ v_o) {
  __shared__ __attribute__((aligned(16))) unsigned short As[128 * 32];
  __shared__ __attribute__((aligned(16))) unsigned short Bs[128 * 32];
  const int tid = threadIdx.x;
  const int w = tid >> 6, lane = tid & 63;
  const int wm = w >> 1, wn = w & 1;
  const int col = lane & 15, quad = lane >> 4;
  // XCD-chunked swizzle: original ids {k, k+8, ...} (same XCD) -> contiguous tiles
  const int nx = gridDim.x;
  const int nwg = nx * gridDim.y;
  const int bidl = blockIdx.y * nx + blockIdx.x;
  const int cpx = nwg >> 3;
  const int swz = (bidl & 7) * cpx + (bidl >> 3);
  const int m0 = (swz / nx) * 128, n0 = (swz % nx) * 128;
  const f32x4 fzero = {0.f, 0.f, 0.f, 0.f};
  f32x4 acc[4][4];
#pragma unroll
  for (int i = 0; i < 4; i++)
#pragma unroll
    for (int j = 0; j < 4; j++) acc[i][j] = fzero;

  for (int k0 = 0; k0 < K; k0 += 32) {
    __syncthreads();
#pragma unroll
    for (int it = 0; it < 2; it++) {
      int c = it * 256 + tid;  // 512 16B-chunks per 128x32 tile
      GLD_LDS(A + (size_t)(m0 + (c >> 2)) * K + k0 + (c & 3) * 8, &As[c * 8]);
      GLD_LDS(Bt + (size_t)(n0 + (c >> 2)) * K + k0 + (c & 3) * 8, &Bs[c * 8]);
    }
    __syncthreads();
    f16x8 af[4], bfr[4];
#pragma unroll
    for (int mi = 0; mi < 4; mi++)
      af[mi] = frag_ld(&As[(wm * 64 + mi * 16 + col) * 32 + quad * 8]);
#pragma unroll
    for (int ni = 0; ni < 4; ni++)
      bfr[ni] = frag_ld(&Bs[(wn * 64 + ni * 16 + col) * 32 + quad * 8]);
#pragma unroll
    for (int mi = 0; mi < 4; mi++)
#pragma unroll
      for (int ni = 0; ni < 4; ni++)
        acc[mi][ni] = mfma16(af[mi], bfr[ni], acc[mi][ni]);
  }

#pragma unroll
  for (int mi = 0; mi < 4; mi++) {
#pragma unroll
    for (int ni = 0; ni < 4; ni++) {
      int gm_b = m0 + wm * 64 + mi * 16 + quad * 4;
      int gn = n0 + wn * 64 + ni * 16 + col;
      float bv = bias[gn];
      if (mode == 1) {
#pragma unroll
        for (int r = 0; r < 4; r++)
          out0[(size_t)(gm_b + r) * N + gn] = acc[mi][ni][r] + bv;
      } else {
        int b = gm_b >> 11, s0 = gm_b & 2047;    // M = 4*2048, s0..s0+3 same b
        int t = gn >> 10, hd = gn & 1023;        // N = 3*1024
        int h = hd >> 6, d = hd & 63;
        size_t bh = (size_t)(b * NHEADS + h);
        if (t == 2) {
          // V: [bh][pblk][d][p], p0 = 8g+4jsub from s0&31 = 16jsub+4g
          int p0 = ((s0 & 12) << 1) | ((s0 & 16) >> 2);
          unsigned short o4[4];
#pragma unroll
          for (int r = 0; r < 4; r++) o4[r] = f2h_bits(acc[mi][ni][r] + bv);
          *(uint2*)&v_o[bh * (DK * S_LEN) + (s0 >> 5) * 2048 + d * 32 + p0] =
              *(const uint2*)o4;
        } else if (t == 0) {
#pragma unroll
          for (int r = 0; r < 4; r++)
            q_o[(bh * S_LEN + s0 + r) * DK + d] =
                f2h_bits((acc[mi][ni][r] + bv) * QSCALE);
        } else {
          // K: [bh][jblk][khalf][j&31][k&31]
          size_t kb = bh * (DK * S_LEN) + (s0 >> 5) * 2048 + (d >> 5) * 1024 +
                      (s0 & 31) * 32 + (d & 31);
#pragma unroll
          for (int r = 0; r < 4; r++)
            k_o[kb + r * 32] = f2h_bits(acc[mi][ni][r] + bv);
        }
      }
    }
  }
}

// ---------------- flash attention: barrier-free, LDS-free K/V, reg dbuf ------
// Chunk = 128 j; 4 waves each own a private 32-j slice. K and V are stored by
// the QKV GEMM in fragment-native per-32-block layouts, so each MFMA operand
// is ONE fully-coalesced 64-lane b128 load (16 consecutive 64B rows) straight
// into registers. No K/V LDS, no main-loop barriers. sched_barrier(0) fences
// pin the issue order {compute A | load A+2 | compute B | load B+3}; the
// waitcnt pass auto-inserts counted vmcnt(8) before each buffer's first use.
// ROUND-6: occupancy was the cap. Across r0-r5, OccupancyPercent == 0.8 x
// (launch_bounds 2nd arg) regardless of VGPR (bound=3 -> 30%, bound=2 -> 20%):
// the min-waves attr pins residency. VGPR=120 permits 4 waves/SIMD, so bound=4
// (cap 128) doubles TLP for this latency-bound kernel. + T5 setprio(1) around
// each COMPUTE: with 4 barrier-free blocks/CU at staggered phases the CU
// scheduler can favor MFMA-phase waves over load-phase waves.
// PV is full-rate 16x16x32 via the lane-local k-permutation
//   pi(quad*8+e) = (e>>2)*16 + quad*4 + (e&3)
// matched by the V j-permutation done in the GEMM epilogue.
// Max-free log2-domain softmax; bias via MFMA C-operand (20 dedup'd LDS b32
// per wave-chunk); cross-wave o/l reduction via LDS at block end. XCD swizzle
// keeps each bh's K/V pinned to one XCD's L2.
__launch_bounds__(256, 4)
__global__ void attn_kernel(const unsigned short* __restrict__ Q,
                            const unsigned short* __restrict__ K,
                            const unsigned short* __restrict__ Vt,
                            const float* __restrict__ rel_bias,
                            unsigned short* __restrict__ ctx) {
  __shared__ __attribute__((aligned(16))) char smem[17664];
  float* brev = (float*)smem;              // 2112 f32 bias table (dead after loop)
  float* red  = (float*)smem;              // 64*68 f32 epilogue scratch (aliases brev)
  float* lred = (float*)(smem + 17408);    // 64 f32

  const int tid = threadIdx.x;
  const int w = tid >> 6, lane = tid & 63;
  const int col = lane & 15, quad = lane >> 4;
  const int bid = blockIdx.x;
  const int xcd = bid & 7, slot = bid >> 3;
  const int bh = (slot >> 5) * 8 + xcd;     // 8 bh per XCD (K/V set = 4MB = L2)
  const int qt = slot & 31;
  const int h = bh & (NHEADS - 1), b = bh >> 4;
  const unsigned short* qp = Q + (size_t)bh * S_LEN * DK;
  const f32x4 fzero = {0.f, 0.f, 0.f, 0.f};

  // windowed reversed bias table (log2e-scaled), idx = j - (q - qt*64) + 63
  const int tbase = 1985 - qt * 64;
#pragma unroll
  for (int it = 0; it < 9; it++) {
    int idx = it * 256 + tid;
    if (idx < 2112) {
      int rel = 3072 - (tbase + idx);
      rel = rel < 0 ? 0 : (rel > 2048 ? 2048 : rel);
      brev[idx] = rel_bias[rel * NHEADS + h] * 1.44269504089f;
    }
  }

  // Q as B-operand frags: qb[qs][ks], q = qt*64 + qs*16 + col
  f16x8 qb[4][2];
#pragma unroll
  for (int qs = 0; qs < 4; qs++)
#pragma unroll
    for (int ks = 0; ks < 2; ks++)
      qb[qs][ks] = frag_ld(qp + (size_t)(qt * 64 + qs * 16 + col) * DK + ks * 32 + quad * 8);

  f32x4 o[4][4];      // partial o[q=qs*16+quad*4+r][d=ds*16+col] over wave's 32 j
  float rsum[4];      // partial l[q=qs*16+col] over lane's j
#pragma unroll
  for (int qs = 0; qs < 4; qs++) {
#pragma unroll
    for (int ds = 0; ds < 4; ds++) o[qs][ds] = fzero;
    rsum[qs] = 0.f;
  }

  // per-lane fragment base inside a 32-block (2048 elems): row*32 + quad*8
  const int koff = col * 32 + quad * 8;
  const unsigned short* kptr = K + (size_t)bh * (DK * S_LEN) + w * 2048 + koff;
  const unsigned short* vptr = Vt + (size_t)bh * (DK * S_LEN) + w * 2048 + koff;
  // bias: idx = ck*128 + w*32 + jsub*16 + quad*4 + r - (qs*16 + col) + 63
  const float* bq = brev + (w * 32 + quad * 4 - col + 63);

  __syncthreads();  // brev ready

#define SB() __builtin_amdgcn_sched_barrier(0)

#define LOADK(dst, p)                                                          \
  dst[0][0] = frag_ld(p);                                                      \
  dst[0][1] = frag_ld(p + 1024);                                               \
  dst[1][0] = frag_ld(p + 512);                                                \
  dst[1][1] = frag_ld(p + 1536);

#define LOADV(dst, p)                                                          \
  _Pragma("unroll")                                                            \
  for (int ds = 0; ds < 4; ds++) dst[ds] = frag_ld(p + ds * 512);

#define COMPUTE(ka, vb)                                                        \
  {                                                                            \
    __builtin_amdgcn_s_setprio(1);                                             \
    float bb[20];                                                              \
    _Pragma("unroll")                                                          \
    for (int g = 0; g < 5; g++)                                                \
      _Pragma("unroll")                                                        \
      for (int r = 0; r < 4; r++) bb[g * 4 + r] = bq[(g - 3) * 16 + r];        \
    _Pragma("unroll")                                                          \
    for (int qs = 0; qs < 4; qs++) {                                           \
      h16x2 pk[4];                                                             \
      _Pragma("unroll")                                                        \
      for (int js = 0; js < 2; js++) {                                         \
        f32x4 bias4;                                                           \
        _Pragma("unroll")                                                      \
        for (int r = 0; r < 4; r++) bias4[r] = bb[(js - qs + 3) * 4 + r];      \
        f32x4 sc = mfma16(ka[js][1], qb[qs][1],                                \
                          mfma16(ka[js][0], qb[qs][0], bias4));                \
        float p0 = __builtin_amdgcn_exp2f(sc[0]);                              \
        float p1 = __builtin_amdgcn_exp2f(sc[1]);                              \
        float p2 = __builtin_amdgcn_exp2f(sc[2]);                              \
        float p3 = __builtin_amdgcn_exp2f(sc[3]);                              \
        rsum[qs] += (p0 + p1) + (p2 + p3);                                     \
        pk[js * 2]     = __builtin_amdgcn_cvt_pkrtz(p0, p1);                   \
        pk[js * 2 + 1] = __builtin_amdgcn_cvt_pkrtz(p2, p3);                   \
      }                                                                        \
      f16x8 pa;                                                                \
      __builtin_memcpy(&pa, pk, 16);                                           \
      _Pragma("unroll")                                                        \
      for (int ds = 0; ds < 4; ds++)                                           \
        o[qs][ds] = mfma16(pa, vb[ds], o[qs][ds]);                             \
    }                                                                          \
    __builtin_amdgcn_s_setprio(0);                                             \
  }

  f16x8 kaA[2][2], kaB[2][2], vbA[4], vbB[4];
  LOADK(kaA, kptr) LOADV(vbA, vptr) kptr += 8192; vptr += 8192;   // chunk 0
  LOADK(kaB, kptr) LOADV(vbB, vptr) kptr += 8192; vptr += 8192;   // chunk 1
  SB();
#pragma unroll 1
  for (int ck = 0; ck < 14; ck += 2) {
    COMPUTE(kaA, vbA) bq += 128;       // chunk ck       (waits vmcnt(8) auto)
    SB();
    LOADK(kaA, kptr) LOADV(vbA, vptr) kptr += 8192; vptr += 8192;  // ck+2
    SB();
    COMPUTE(kaB, vbB) bq += 128;       // chunk ck+1
    SB();
    LOADK(kaB, kptr) LOADV(vbB, vptr) kptr += 8192; vptr += 8192;  // ck+3
    SB();
  }
  COMPUTE(kaA, vbA) bq += 128;         // chunk 14
  COMPUTE(kaB, vbB)                    // chunk 15

  // finish l: sum over quads (j within wave) -> all lanes of col hold wave-partial l[q]
#pragma unroll
  for (int qs = 0; qs < 4; qs++) {
    rsum[qs] += __shfl_xor(rsum[qs], 16);
    rsum[qs] += __shfl_xor(rsum[qs], 32);
  }

  // cross-wave reduction (sequential, in-place; red stride 68 for alignment+banks)
  __syncthreads();
  for (int ws = 3; ws >= 0; ws--) {
    if (w == ws) {
#pragma unroll
      for (int qs = 0; qs < 4; qs++) {
#pragma unroll
        for (int ds = 0; ds < 4; ds++) {
#pragma unroll
          for (int r = 0; r < 4; r++) {
            int q = qs * 16 + quad * 4 + r, d = ds * 16 + col;
            if (ws == 3) red[q * 68 + d] = o[qs][ds][r];
            else         red[q * 68 + d] += o[qs][ds][r];
          }
        }
        int ql = qs * 16 + col;
        if (ws == 3) lred[ql] = rsum[qs];
        else         lred[ql] += rsum[qs];
      }
    }
    __syncthreads();
  }

  // cooperative readout: wave w handles q rows [w*16, w*16+16)
#pragma unroll
  for (int pass = 0; pass < 4; pass++) {
    int ql = w * 16 + pass * 4 + quad;
    f32x4 ov = *(const f32x4*)&red[ql * 68 + col * 4];
    float inv = 1.0f / lred[ql];
    h16x2 lo = __builtin_amdgcn_cvt_pkrtz(ov[0] * inv, ov[1] * inv);
    h16x2 hi = __builtin_amdgcn_cvt_pkrtz(ov[2] * inv, ov[3] * inv);
    uint2 pkd;
    __builtin_memcpy(&pkd.x, &lo, 4);
    __builtin_memcpy(&pkd.y, &hi, 4);
    *(uint2*)&ctx[((size_t)b * S_LEN + qt * 64 + ql) * DMODEL + h * DK + col * 4] = pkd;
  }
}

extern "C" void kernel_launch(void* const* d_in, const int* in_sizes, int n_in,
                              void* d_out, int out_size, void* d_ws, size_t ws_size,
                              hipStream_t stream) {
  (void)in_sizes; (void)n_in; (void)out_size; (void)ws_size;
  const float* x        = (const float*)d_in[0];
  const float* W_qkv    = (const float*)d_in[1];
  const float* b_qkv    = (const float*)d_in[2];
  const float* W_out    = (const float*)d_in[3];
  const float* b_out    = (const float*)d_in[4];
  const float* rel_bias = (const float*)d_in[5];
  float* out = (float*)d_out;

  char* ws = (char*)d_ws;
  unsigned short* xh     = (unsigned short*)(ws + 0);          // [8192,1024] f16 (aliases ctx)
  unsigned short* ctxh   = (unsigned short*)(ws + 0);
  unsigned short* Wqkv_t = (unsigned short*)(ws + 16777216);   // [3072,1024] f16
  unsigned short* Wout_t = (unsigned short*)(ws + 23068672);   // [1024,1024] f16
  unsigned short* Qb     = (unsigned short*)(ws + 25165824);   // [4,16,2048,64] f16
  unsigned short* Kb     = (unsigned short*)(ws + 41943040);   // [4,16,64blk,2,32,32] f16
  unsigned short* Vtb    = (unsigned short*)(ws + 58720256);   // [4,16,64blk,64,32] f16

  convert_f32_f16<<<(8192 * 1024 / 4 + 255) / 256, 256, 0, stream>>>(x, xh, 8192 * 1024 / 4);
  transpose_f32_f16<<<dim3(3072 / 32, 1024 / 32), dim3(32, 8), 0, stream>>>(W_qkv, Wqkv_t, 1024, 3072);
  transpose_f32_f16<<<dim3(1024 / 32, 1024 / 32), dim3(32, 8), 0, stream>>>(W_out, Wout_t, 1024, 1024);
  gemm_bt<<<dim3(3072 / 128, 8192 / 128), 256, 0, stream>>>(
      xh, Wqkv_t, 8192, 3072, 1024, 0, b_qkv, nullptr, Qb, Kb, Vtb);
  attn_kernel<<<4 * NHEADS * (S_LEN / 64), 256, 0, stream>>>(Qb, Kb, Vtb, rel_bias, ctxh);
  gemm_bt<<<dim3(1024 / 128, 8192 / 128), 256, 0, stream>>>(
      ctxh, Wout_t, 8192, 1024, 1024, 1, b_out, out, nullptr, nullptr, nullptr);
}

// Round 7
// 894.026 us; speedup vs baseline: 1.3613x; 1.3613x over previous
//
#include <hip/hip_runtime.h>

#define S_LEN 2048
#define NHEADS 16
#define DK 64
#define DMODEL 1024
#define QSCALE 0.18033688011f  /* 0.125 * log2(e) */

typedef float f32x4 __attribute__((ext_vector_type(4)));
typedef _Float16 f16x8 __attribute__((ext_vector_type(8)));
typedef _Float16 f16x4 __attribute__((ext_vector_type(4)));
typedef __fp16 h16x2 __attribute__((ext_vector_type(2)));   // cvt_pkrtz native type

__device__ __forceinline__ unsigned short f2h_bits(float f) {
  _Float16 h = (_Float16)f;
  unsigned short u; __builtin_memcpy(&u, &h, 2); return u;
}

__device__ __forceinline__ f32x4 mfma16(f16x8 a, f16x8 b, f32x4 c) {
  return __builtin_amdgcn_mfma_f32_16x16x32_f16(a, b, c, 0, 0, 0);
}
__device__ __forceinline__ f16x8 frag_ld(const unsigned short* p) {
  return *(const f16x8*)p;
}

#define GLD_LDS(g, l)                                                          \
  __builtin_amdgcn_global_load_lds(                                            \
      (const __attribute__((address_space(1))) void*)(g),                      \
      (__attribute__((address_space(3))) void*)(l), 16, 0, 0)

// ---------------- fp32 -> fp16 convert (contiguous) ----------------
__global__ void convert_f32_f16(const float* __restrict__ in,
                                unsigned short* __restrict__ out, int n4) {
  int i = blockIdx.x * blockDim.x + threadIdx.x;
  if (i < n4) {
    f32x4 v = *(const f32x4*)(in + (size_t)i * 4);
    unsigned short o[4];
#pragma unroll
    for (int j = 0; j < 4; j++) o[j] = f2h_bits(v[j]);
    *(uint2*)(out + (size_t)i * 4) = *(const uint2*)o;
  }
}

// ---------------- fp32 -> fp16 transpose ----------------
__global__ void transpose_f32_f16(const float* __restrict__ in,
                                  unsigned short* __restrict__ out, int R, int C) {
  __shared__ unsigned short tile[32][33];
  int bx = blockIdx.x * 32, by = blockIdx.y * 32;
  int tx = threadIdx.x, ty = threadIdx.y;
  for (int i = ty; i < 32; i += 8)
    tile[i][tx] = f2h_bits(in[(size_t)(by + i) * C + bx + tx]);
  __syncthreads();
  for (int i = ty; i < 32; i += 8)
    out[(size_t)(bx + i) * R + by + tx] = tile[tx][i];
}

// ---------------- 128x128 MFMA GEMM, B^T input (m97 structure), fp16 in fp32 acc
// + T1 bijective XCD-chunked block swizzle.
// Mode-0 epilogue (ROUND 7): the old epilogue issued ~144 scattered 2-8B global
// stores per thread (K: 2B at 64B stride). Each head's output sub-tile is a
// CONTIGUOUS 16KB region in all three layouts (base = out + bh*131072 +
// s_base*64), so we build the exact byte image in the (dead) 16KB As/Bs LDS
// (two passes, one head each; ni rotated by quad to spread LDS banks) and dump
// it with lane-consecutive 16B coalesced stores.
//   K: [bh][jblk=s>>5][khalf=d>>5][s&31][k&31]
//   V: [bh][pblk=s>>5][d][p]  with within-32 j-permutation p = 8g+4jsub+r
//      (from s&31 = 16jsub+4g+r) so attn PV B-frags are contiguous 16B.
__launch_bounds__(256)
__global__ void gemm_bt(const unsigned short* __restrict__ A,
                        const unsigned short* __restrict__ Bt,
                        int M, int N, int K, int mode,
                        const float* __restrict__ bias,
                        float* __restrict__ out0,
                        unsigned short* __restrict__ q_o,
                        unsigned short* __restrict__ k_o,
                        unsigned short* __restrict__ v_o) {
  __shared__ __attribute__((aligned(16))) unsigned short sAB[2 * 128 * 32];
  unsigned short* As = sAB;
  unsigned short* Bs = sAB + 128 * 32;
  const int tid = threadIdx.x;
  const int w = tid >> 6, lane = tid & 63;
  const int wm = w >> 1, wn = w & 1;
  const int col = lane & 15, quad = lane >> 4;
  // XCD-chunked swizzle: original ids {k, k+8, ...} (same XCD) -> contiguous tiles
  const int nx = gridDim.x;
  const int nwg = nx * gridDim.y;
  const int bidl = blockIdx.y * nx + blockIdx.x;
  const int cpx = nwg >> 3;
  const int swz = (bidl & 7) * cpx + (bidl >> 3);
  const int m0 = (swz / nx) * 128, n0 = (swz % nx) * 128;
  const f32x4 fzero = {0.f, 0.f, 0.f, 0.f};
  f32x4 acc[4][4];
#pragma unroll
  for (int i = 0; i < 4; i++)
#pragma unroll
    for (int j = 0; j < 4; j++) acc[i][j] = fzero;

  for (int k0 = 0; k0 < K; k0 += 32) {
    __syncthreads();
#pragma unroll
    for (int it = 0; it < 2; it++) {
      int c = it * 256 + tid;  // 512 16B-chunks per 128x32 tile
      GLD_LDS(A + (size_t)(m0 + (c >> 2)) * K + k0 + (c & 3) * 8, &As[c * 8]);
      GLD_LDS(Bt + (size_t)(n0 + (c >> 2)) * K + k0 + (c & 3) * 8, &Bs[c * 8]);
    }
    __syncthreads();
    f16x8 af[4], bfr[4];
#pragma unroll
    for (int mi = 0; mi < 4; mi++)
      af[mi] = frag_ld(&As[(wm * 64 + mi * 16 + col) * 32 + quad * 8]);
#pragma unroll
    for (int ni = 0; ni < 4; ni++)
      bfr[ni] = frag_ld(&Bs[(wn * 64 + ni * 16 + col) * 32 + quad * 8]);
#pragma unroll
    for (int mi = 0; mi < 4; mi++)
#pragma unroll
      for (int ni = 0; ni < 4; ni++)
        acc[mi][ni] = mfma16(af[mi], bfr[ni], acc[mi][ni]);
  }

  if (mode == 1) {
#pragma unroll
    for (int mi = 0; mi < 4; mi++) {
#pragma unroll
      for (int ni = 0; ni < 4; ni++) {
        int gm_b = m0 + wm * 64 + mi * 16 + quad * 4;
        int gn = n0 + wn * 64 + ni * 16 + col;
        float bv = bias[gn];
#pragma unroll
        for (int r = 0; r < 4; r++)
          out0[(size_t)(gm_b + r) * N + gn] = acc[mi][ni][r] + bv;
      }
    }
  } else {
    // coalesced QKV epilogue via LDS image; t uniform per block (128 | 1024)
    const int t  = n0 >> 10;                 // 0=Q 1=K 2=V
    const int h0 = (n0 & 1023) >> 6;
    const int bI = m0 >> 11;
    const int sB = m0 & 2047;
    const float scl = (t == 0) ? QSCALE : 1.0f;
    unsigned short* img = sAB;               // 16 KB = one head's region image
#pragma unroll
    for (int hh = 0; hh < 2; hh++) {
      __syncthreads();                       // img free / prev pass stores done
      if (wn == hh) {
#pragma unroll
        for (int mi = 0; mi < 4; mi++) {
#pragma unroll
          for (int ii = 0; ii < 4; ii++) {
            const int ni = (quad + ii) & 3;  // quad-rotated: spread LDS banks
            const f32x4 a = acc[mi][ni];
            const int d = ni * 16 + col;     // 0..63
            const float bv = bias[n0 + hh * 64 + ni * 16 + col];
            if (t == 0) {
              // Q image: [srel][d]
              const int o0 = (wm * 64 + mi * 16 + quad * 4) * 64 + d;
#pragma unroll
              for (int r = 0; r < 4; r++)
                img[o0 + r * 64] = f2h_bits((a[r] + bv) * scl);
            } else if (t == 1) {
              // K image: [jblk][khalf][srel&31][k&31]
              const int o0 = (wm * 2 + (mi >> 1)) * 2048 + (d >> 5) * 1024 +
                             ((mi & 1) * 16 + quad * 4) * 32 + (d & 31);
#pragma unroll
              for (int r = 0; r < 4; r++)
                img[o0 + r * 32] = f2h_bits(a[r] + bv);
            } else {
              // V image: [pblk][d][p], p = 8*quad + 4*(mi&1) + r
              const int o0 =
                  (wm * 2 + (mi >> 1)) * 2048 + d * 32 + quad * 8 + (mi & 1) * 4;
              unsigned short o4[4];
#pragma unroll
              for (int r = 0; r < 4; r++) o4[r] = f2h_bits(a[r] + bv);
              *(uint2*)&img[o0] = *(const uint2*)o4;
            }
          }
        }
      }
      __syncthreads();                       // img complete
      unsigned short* dst =
          ((t == 0) ? q_o : (t == 1) ? k_o : v_o) +
          (size_t)(bI * NHEADS + h0 + hh) * 131072 + (size_t)sB * 64;
#pragma unroll
      for (int i2 = 0; i2 < 4; i2++)
        *(f16x8*)(dst + i2 * 2048 + tid * 8) =
            *(const f16x8*)&img[i2 * 2048 + tid * 8];
    }
  }
}

// ---------------- flash attention: barrier-free, LDS-free K/V, reg dbuf ------
// Chunk = 128 j; 4 waves each own a private 32-j slice. K and V are stored by
// the QKV GEMM in fragment-native per-32-block layouts, so each MFMA operand
// is ONE fully-coalesced 64-lane b128 load (16 consecutive 64B rows) straight
// into registers. No K/V LDS, no main-loop barriers. sched_barrier(0) fences
// pin the issue order {compute A | load A+2 | compute B | load B+3}; the
// waitcnt pass auto-inserts counted vmcnt(8) before each buffer's first use.
// ROUND-7: launch_bounds min-waves attr REMOVED. r6's (256,4) budgeted 128
// total regs/wave (64 arch + 64 acc) -> everything spilled (FETCH 1.7GB,
// 1037us). With no attr, the allocator settles ~120 arch VGPR and hardware
// residency follows actual use: 4 blocks/CU (480<=512 regs, 71.6<=160KB LDS),
// doubling TLP vs the pinned-2 config without any forced cap.
// T5 setprio(1) around COMPUTE: staggered barrier-free blocks let the CU
// scheduler favor MFMA-phase waves.
// PV is full-rate 16x16x32 via the lane-local k-permutation
//   pi(quad*8+e) = (e>>2)*16 + quad*4 + (e&3)
// matched by the V j-permutation done in the GEMM epilogue.
// Max-free log2-domain softmax; bias via MFMA C-operand (20 dedup'd LDS b32
// per wave-chunk); cross-wave o/l reduction via LDS at block end. XCD swizzle
// keeps each bh's K/V pinned to one XCD's L2.
__launch_bounds__(256)
__global__ void attn_kernel(const unsigned short* __restrict__ Q,
                            const unsigned short* __restrict__ K,
                            const unsigned short* __restrict__ Vt,
                            const float* __restrict__ rel_bias,
                            unsigned short* __restrict__ ctx) {
  __shared__ __attribute__((aligned(16))) char smem[17664];
  float* brev = (float*)smem;              // 2112 f32 bias table (dead after loop)
  float* red  = (float*)smem;              // 64*68 f32 epilogue scratch (aliases brev)
  float* lred = (float*)(smem + 17408);    // 64 f32

  const int tid = threadIdx.x;
  const int w = tid >> 6, lane = tid & 63;
  const int col = lane & 15, quad = lane >> 4;
  const int bid = blockIdx.x;
  const int xcd = bid & 7, slot = bid >> 3;
  const int bh = (slot >> 5) * 8 + xcd;     // 8 bh per XCD (K/V set = 4MB = L2)
  const int qt = slot & 31;
  const int h = bh & (NHEADS - 1), b = bh >> 4;
  const unsigned short* qp = Q + (size_t)bh * S_LEN * DK;
  const f32x4 fzero = {0.f, 0.f, 0.f, 0.f};

  // windowed reversed bias table (log2e-scaled), idx = j - (q - qt*64) + 63
  const int tbase = 1985 - qt * 64;
#pragma unroll
  for (int it = 0; it < 9; it++) {
    int idx = it * 256 + tid;
    if (idx < 2112) {
      int rel = 3072 - (tbase + idx);
      rel = rel < 0 ? 0 : (rel > 2048 ? 2048 : rel);
      brev[idx] = rel_bias[rel * NHEADS + h] * 1.44269504089f;
    }
  }

  // Q as B-operand frags: qb[qs][ks], q = qt*64 + qs*16 + col
  f16x8 qb[4][2];
#pragma unroll
  for (int qs = 0; qs < 4; qs++)
#pragma unroll
    for (int ks = 0; ks < 2; ks++)
      qb[qs][ks] = frag_ld(qp + (size_t)(qt * 64 + qs * 16 + col) * DK + ks * 32 + quad * 8);

  f32x4 o[4][4];      // partial o[q=qs*16+quad*4+r][d=ds*16+col] over wave's 32 j
  float rsum[4];      // partial l[q=qs*16+col] over lane's j
#pragma unroll
  for (int qs = 0; qs < 4; qs++) {
#pragma unroll
    for (int ds = 0; ds < 4; ds++) o[qs][ds] = fzero;
    rsum[qs] = 0.f;
  }

  // per-lane fragment base inside a 32-block (2048 elems): row*32 + quad*8
  const int koff = col * 32 + quad * 8;
  const unsigned short* kptr = K + (size_t)bh * (DK * S_LEN) + w * 2048 + koff;
  const unsigned short* vptr = Vt + (size_t)bh * (DK * S_LEN) + w * 2048 + koff;
  // bias: idx = ck*128 + w*32 + jsub*16 + quad*4 + r - (qs*16 + col) + 63
  const float* bq = brev + (w * 32 + quad * 4 - col + 63);

  __syncthreads();  // brev ready

#define SB() __builtin_amdgcn_sched_barrier(0)

#define LOADK(dst, p)                                                          \
  dst[0][0] = frag_ld(p);                                                      \
  dst[0][1] = frag_ld(p + 1024);                                               \
  dst[1][0] = frag_ld(p + 512);                                                \
  dst[1][1] = frag_ld(p + 1536);

#define LOADV(dst, p)                                                          \
  _Pragma("unroll")                                                            \
  for (int ds = 0; ds < 4; ds++) dst[ds] = frag_ld(p + ds * 512);

#define COMPUTE(ka, vb)                                                        \
  {                                                                            \
    __builtin_amdgcn_s_setprio(1);                                             \
    float bb[20];                                                              \
    _Pragma("unroll")                                                          \
    for (int g = 0; g < 5; g++)                                                \
      _Pragma("unroll")                                                        \
      for (int r = 0; r < 4; r++) bb[g * 4 + r] = bq[(g - 3) * 16 + r];        \
    _Pragma("unroll")                                                          \
    for (int qs = 0; qs < 4; qs++) {                                           \
      h16x2 pk[4];                                                             \
      _Pragma("unroll")                                                        \
      for (int js = 0; js < 2; js++) {                                         \
        f32x4 bias4;                                                           \
        _Pragma("unroll")                                                      \
        for (int r = 0; r < 4; r++) bias4[r] = bb[(js - qs + 3) * 4 + r];      \
        f32x4 sc = mfma16(ka[js][1], qb[qs][1],                                \
                          mfma16(ka[js][0], qb[qs][0], bias4));                \
        float p0 = __builtin_amdgcn_exp2f(sc[0]);                              \
        float p1 = __builtin_amdgcn_exp2f(sc[1]);                              \
        float p2 = __builtin_amdgcn_exp2f(sc[2]);                              \
        float p3 = __builtin_amdgcn_exp2f(sc[3]);                              \
        rsum[qs] += (p0 + p1) + (p2 + p3);                                     \
        pk[js * 2]     = __builtin_amdgcn_cvt_pkrtz(p0, p1);                   \
        pk[js * 2 + 1] = __builtin_amdgcn_cvt_pkrtz(p2, p3);                   \
      }                                                                        \
      f16x8 pa;                                                                \
      __builtin_memcpy(&pa, pk, 16);                                           \
      _Pragma("unroll")                                                        \
      for (int ds = 0; ds < 4; ds++)                                           \
        o[qs][ds] = mfma16(pa, vb[ds], o[qs][ds]);                             \
    }                                                                          \
    __builtin_amdgcn_s_setprio(0);                                             \
  }

  f16x8 kaA[2][2], kaB[2][2], vbA[4], vbB[4];
  LOADK(kaA, kptr) LOADV(vbA, vptr) kptr += 8192; vptr += 8192;   // chunk 0
  LOADK(kaB, kptr) LOADV(vbB, vptr) kptr += 8192; vptr += 8192;   // chunk 1
  SB();
#pragma unroll 1
  for (int ck = 0; ck < 14; ck += 2) {
    COMPUTE(kaA, vbA) bq += 128;       // chunk ck       (waits vmcnt(8) auto)
    SB();
    LOADK(kaA, kptr) LOADV(vbA, vptr) kptr += 8192; vptr += 8192;  // ck+2
    SB();
    COMPUTE(kaB, vbB) bq += 128;       // chunk ck+1
    SB();
    LOADK(kaB, kptr) LOADV(vbB, vptr) kptr += 8192; vptr += 8192;  // ck+3
    SB();
  }
  COMPUTE(kaA, vbA) bq += 128;         // chunk 14
  COMPUTE(kaB, vbB)                    // chunk 15

  // finish l: sum over quads (j within wave) -> all lanes of col hold wave-partial l[q]
#pragma unroll
  for (int qs = 0; qs < 4; qs++) {
    rsum[qs] += __shfl_xor(rsum[qs], 16);
    rsum[qs] += __shfl_xor(rsum[qs], 32);
  }

  // cross-wave reduction (sequential, in-place; red stride 68 for alignment+banks)
  __syncthreads();
  for (int ws = 3; ws >= 0; ws--) {
    if (w == ws) {
#pragma unroll
      for (int qs = 0; qs < 4; qs++) {
#pragma unroll
        for (int ds = 0; ds < 4; ds++) {
#pragma unroll
          for (int r = 0; r < 4; r++) {
            int q = qs * 16 + quad * 4 + r, d = ds * 16 + col;
            if (ws == 3) red[q * 68 + d] = o[qs][ds][r];
            else         red[q * 68 + d] += o[qs][ds][r];
          }
        }
        int ql = qs * 16 + col;
        if (ws == 3) lred[ql] = rsum[qs];
        else         lred[ql] += rsum[qs];
      }
    }
    __syncthreads();
  }

  // cooperative readout: wave w handles q rows [w*16, w*16+16)
#pragma unroll
  for (int pass = 0; pass < 4; pass++) {
    int ql = w * 16 + pass * 4 + quad;
    f32x4 ov = *(const f32x4*)&red[ql * 68 + col * 4];
    float inv = 1.0f / lred[ql];
    h16x2 lo = __builtin_amdgcn_cvt_pkrtz(ov[0] * inv, ov[1] * inv);
    h16x2 hi = __builtin_amdgcn_cvt_pkrtz(ov[2] * inv, ov[3] * inv);
    uint2 pkd;
    __builtin_memcpy(&pkd.x, &lo, 4);
    __builtin_memcpy(&pkd.y, &hi, 4);
    *(uint2*)&ctx[((size_t)b * S_LEN + qt * 64 + ql) * DMODEL + h * DK + col * 4] = pkd;
  }
}

extern "C" void kernel_launch(void* const* d_in, const int* in_sizes, int n_in,
                              void* d_out, int out_size, void* d_ws, size_t ws_size,
                              hipStream_t stream) {
  (void)in_sizes; (void)n_in; (void)out_size; (void)ws_size;
  const float* x        = (const float*)d_in[0];
  const float* W_qkv    = (const float*)d_in[1];
  const float* b_qkv    = (const float*)d_in[2];
  const float* W_out    = (const float*)d_in[3];
  const float* b_out    = (const float*)d_in[4];
  const float* rel_bias = (const float*)d_in[5];
  float* out = (float*)d_out;

  char* ws = (char*)d_ws;
  unsigned short* xh     = (unsigned short*)(ws + 0);          // [8192,1024] f16 (aliases ctx)
  unsigned short* ctxh   = (unsigned short*)(ws + 0);
  unsigned short* Wqkv_t = (unsigned short*)(ws + 16777216);   // [3072,1024] f16
  unsigned short* Wout_t = (unsigned short*)(ws + 23068672);   // [1024,1024] f16
  unsigned short* Qb     = (unsigned short*)(ws + 25165824);   // [4,16,2048,64] f16
  unsigned short* Kb     = (unsigned short*)(ws + 41943040);   // [4,16,64blk,2,32,32] f16
  unsigned short* Vtb    = (unsigned short*)(ws + 58720256);   // [4,16,64blk,64,32] f16

  convert_f32_f16<<<(8192 * 1024 / 4 + 255) / 256, 256, 0, stream>>>(x, xh, 8192 * 1024 / 4);
  transpose_f32_f16<<<dim3(3072 / 32, 1024 / 32), dim3(32, 8), 0, stream>>>(W_qkv, Wqkv_t, 1024, 3072);
  transpose_f32_f16<<<dim3(1024 / 32, 1024 / 32), dim3(32, 8), 0, stream>>>(W_out, Wout_t, 1024, 1024);
  gemm_bt<<<dim3(3072 / 128, 8192 / 128), 256, 0, stream>>>(
      xh, Wqkv_t, 8192, 3072, 1024, 0, b_qkv, nullptr, Qb, Kb, Vtb);
  attn_kernel<<<4 * NHEADS * (S_LEN / 64), 256, 0, stream>>>(Qb, Kb, Vtb, rel_bias, ctxh);
  gemm_bt<<<dim3(1024 / 128, 8192 / 128), 256, 0, stream>>>(
      ctxh, Wout_t, 8192, 1024, 1024, 1, b_out, out, nullptr, nullptr, nullptr);
}

// Round 8
// 356.076 us; speedup vs baseline: 3.4179x; 2.5108x over previous
//
#include <hip/hip_runtime.h>

#define S_LEN 2048
#define NHEADS 16
#define DK 64
#define DMODEL 1024
#define QSCALE 0.18033688011f  /* 0.125 * log2(e) */

typedef float f32x4 __attribute__((ext_vector_type(4)));
typedef _Float16 f16x8 __attribute__((ext_vector_type(8)));
typedef _Float16 f16x4 __attribute__((ext_vector_type(4)));
typedef __fp16 h16x2 __attribute__((ext_vector_type(2)));   // cvt_pkrtz native type

__device__ __forceinline__ unsigned short f2h_bits(float f) {
  _Float16 h = (_Float16)f;
  unsigned short u; __builtin_memcpy(&u, &h, 2); return u;
}

__device__ __forceinline__ f32x4 mfma16(f16x8 a, f16x8 b, f32x4 c) {
  return __builtin_amdgcn_mfma_f32_16x16x32_f16(a, b, c, 0, 0, 0);
}
__device__ __forceinline__ f16x8 frag_ld(const unsigned short* p) {
  return *(const f16x8*)p;
}

#define GLD_LDS(g, l)                                                          \
  __builtin_amdgcn_global_load_lds(                                            \
      (const __attribute__((address_space(1))) void*)(g),                      \
      (__attribute__((address_space(3))) void*)(l), 16, 0, 0)

// ---------------- fp32 -> fp16 convert (contiguous) ----------------
__global__ void convert_f32_f16(const float* __restrict__ in,
                                unsigned short* __restrict__ out, int n4) {
  int i = blockIdx.x * blockDim.x + threadIdx.x;
  if (i < n4) {
    f32x4 v = *(const f32x4*)(in + (size_t)i * 4);
    unsigned short o[4];
#pragma unroll
    for (int j = 0; j < 4; j++) o[j] = f2h_bits(v[j]);
    *(uint2*)(out + (size_t)i * 4) = *(const uint2*)o;
  }
}

// ---------------- fp32 -> fp16 transpose ----------------
__global__ void transpose_f32_f16(const float* __restrict__ in,
                                  unsigned short* __restrict__ out, int R, int C) {
  __shared__ unsigned short tile[32][33];
  int bx = blockIdx.x * 32, by = blockIdx.y * 32;
  int tx = threadIdx.x, ty = threadIdx.y;
  for (int i = ty; i < 32; i += 8)
    tile[i][tx] = f2h_bits(in[(size_t)(by + i) * C + bx + tx]);
  __syncthreads();
  for (int i = ty; i < 32; i += 8)
    out[(size_t)(bx + i) * R + by + tx] = tile[tx][i];
}

// ---------------- 128x128 MFMA GEMM, B^T input (m97 structure), fp16 in fp32 acc
// + T1 bijective XCD-chunked block swizzle.
// Mode-0 epilogue: each head's output sub-tile is a CONTIGUOUS 16KB region in
// all three Q/K/V layouts (base = out + bh*131072 + s_base*64). Build the exact
// byte image in the (dead) 16KB As/Bs LDS, then dump with lane-consecutive 16B
// coalesced stores.
// ROUND-8 FIX: r7's image build indexed acc[mi][(quad+ii)&3] -- a RUNTIME index
// into an ext_vector array (rule #20) -> the whole acc[4][4] demoted to
// scratch, every K-loop MFMA did a scratch round-trip (WRITE_SIZE 3.0GB,
// VGPR 88, 505us). All acc indices are now compile-time constants.
//   K: [bh][jblk=s>>5][khalf=d>>5][s&31][k&31]
//   V: [bh][pblk=s>>5][d][p]  with within-32 j-permutation p = 8g+4jsub+r
//      (from s&31 = 16jsub+4g+r) so attn PV B-frags are contiguous 16B.
__launch_bounds__(256)
__global__ void gemm_bt(const unsigned short* __restrict__ A,
                        const unsigned short* __restrict__ Bt,
                        int M, int N, int K, int mode,
                        const float* __restrict__ bias,
                        float* __restrict__ out0,
                        unsigned short* __restrict__ q_o,
                        unsigned short* __restrict__ k_o,
                        unsigned short* __restrict__ v_o) {
  __shared__ __attribute__((aligned(16))) unsigned short sAB[2 * 128 * 32];
  unsigned short* As = sAB;
  unsigned short* Bs = sAB + 128 * 32;
  const int tid = threadIdx.x;
  const int w = tid >> 6, lane = tid & 63;
  const int wm = w >> 1, wn = w & 1;
  const int col = lane & 15, quad = lane >> 4;
  // XCD-chunked swizzle: original ids {k, k+8, ...} (same XCD) -> contiguous tiles
  const int nx = gridDim.x;
  const int nwg = nx * gridDim.y;
  const int bidl = blockIdx.y * nx + blockIdx.x;
  const int cpx = nwg >> 3;
  const int swz = (bidl & 7) * cpx + (bidl >> 3);
  const int m0 = (swz / nx) * 128, n0 = (swz % nx) * 128;
  const f32x4 fzero = {0.f, 0.f, 0.f, 0.f};
  f32x4 acc[4][4];
#pragma unroll
  for (int i = 0; i < 4; i++)
#pragma unroll
    for (int j = 0; j < 4; j++) acc[i][j] = fzero;

  for (int k0 = 0; k0 < K; k0 += 32) {
    __syncthreads();
#pragma unroll
    for (int it = 0; it < 2; it++) {
      int c = it * 256 + tid;  // 512 16B-chunks per 128x32 tile
      GLD_LDS(A + (size_t)(m0 + (c >> 2)) * K + k0 + (c & 3) * 8, &As[c * 8]);
      GLD_LDS(Bt + (size_t)(n0 + (c >> 2)) * K + k0 + (c & 3) * 8, &Bs[c * 8]);
    }
    __syncthreads();
    f16x8 af[4], bfr[4];
#pragma unroll
    for (int mi = 0; mi < 4; mi++)
      af[mi] = frag_ld(&As[(wm * 64 + mi * 16 + col) * 32 + quad * 8]);
#pragma unroll
    for (int ni = 0; ni < 4; ni++)
      bfr[ni] = frag_ld(&Bs[(wn * 64 + ni * 16 + col) * 32 + quad * 8]);
#pragma unroll
    for (int mi = 0; mi < 4; mi++)
#pragma unroll
      for (int ni = 0; ni < 4; ni++)
        acc[mi][ni] = mfma16(af[mi], bfr[ni], acc[mi][ni]);
  }

  if (mode == 1) {
#pragma unroll
    for (int mi = 0; mi < 4; mi++) {
#pragma unroll
      for (int ni = 0; ni < 4; ni++) {
        int gm_b = m0 + wm * 64 + mi * 16 + quad * 4;
        int gn = n0 + wn * 64 + ni * 16 + col;
        float bv = bias[gn];
#pragma unroll
        for (int r = 0; r < 4; r++)
          out0[(size_t)(gm_b + r) * N + gn] = acc[mi][ni][r] + bv;
      }
    }
  } else {
    // coalesced QKV epilogue via LDS image; t uniform per block (128 | 1024)
    const int t  = n0 >> 10;                 // 0=Q 1=K 2=V
    const int h0 = (n0 & 1023) >> 6;
    const int bI = m0 >> 11;
    const int sB = m0 & 2047;
    unsigned short* img = sAB;               // 16 KB = one head's region image
#pragma unroll
    for (int hh = 0; hh < 2; hh++) {
      __syncthreads();                       // img free / prev pass stores done
      if (wn == hh) {
#pragma unroll
        for (int mi = 0; mi < 4; mi++) {
#pragma unroll
          for (int ni = 0; ni < 4; ni++) {   // STATIC index (rule #20)
            const f32x4 a = acc[mi][ni];
            const int d = ni * 16 + col;     // 0..63
            const float bv = bias[n0 + hh * 64 + ni * 16 + col];
            if (t == 0) {
              // Q image: [srel][d]
              const int o0 = (wm * 64 + mi * 16 + quad * 4) * 64 + d;
#pragma unroll
              for (int r = 0; r < 4; r++)
                img[o0 + r * 64] = f2h_bits((a[r] + bv) * QSCALE);
            } else if (t == 1) {
              // K image: [jblk][khalf][srel&31][k&31]
              const int o0 = (wm * 2 + (mi >> 1)) * 2048 + (d >> 5) * 1024 +
                             ((mi & 1) * 16 + quad * 4) * 32 + (d & 31);
#pragma unroll
              for (int r = 0; r < 4; r++)
                img[o0 + r * 32] = f2h_bits(a[r] + bv);
            } else {
              // V image: [pblk][d][p], p = 8*quad + 4*(mi&1) + r
              const int o0 =
                  (wm * 2 + (mi >> 1)) * 2048 + d * 32 + quad * 8 + (mi & 1) * 4;
              unsigned short o4[4];
#pragma unroll
              for (int r = 0; r < 4; r++) o4[r] = f2h_bits(a[r] + bv);
              *(uint2*)&img[o0] = *(const uint2*)o4;
            }
          }
        }
      }
      __syncthreads();                       // img complete
      unsigned short* dst =
          ((t == 0) ? q_o : (t == 1) ? k_o : v_o) +
          (size_t)(bI * NHEADS + h0 + hh) * 131072 + (size_t)sB * 64;
#pragma unroll
      for (int i2 = 0; i2 < 4; i2++)
        *(f16x8*)(dst + i2 * 2048 + tid * 8) =
            *(const f16x8*)&img[i2 * 2048 + tid * 8];
    }
  }
}

// ---------------- flash attention: barrier-free, LDS-free K/V, reg dbuf ------
// Chunk = 128 j; 4 waves each own a private 32-j slice. K and V are stored by
// the QKV GEMM in fragment-native per-32-block layouts, so each MFMA operand
// is ONE fully-coalesced 64-lane b128 load (16 consecutive 64B rows) straight
// into registers. No K/V LDS, no main-loop barriers. sched_barrier(0) fences
// pin the issue order {compute A | load A+2 | compute B | load B+3}; the
// waitcnt pass auto-inserts counted vmcnt(8) before each buffer's first use.
// No launch_bounds min-waves attr (r6's (256,4) forced a 128-reg budget ->
// total spill). Allocator settles ~120 arch VGPR; residency follows use:
// 4 blocks/CU (480<=512 regs, 71.6<=160KB LDS).
// T5 setprio(1) around COMPUTE: staggered barrier-free blocks let the CU
// scheduler favor MFMA-phase waves.
// PV is full-rate 16x16x32 via the lane-local k-permutation
//   pi(quad*8+e) = (e>>2)*16 + quad*4 + (e&3)
// matched by the V j-permutation done in the GEMM epilogue.
// Max-free log2-domain softmax; bias via MFMA C-operand (20 dedup'd LDS b32
// per wave-chunk); cross-wave o/l reduction via LDS at block end. XCD swizzle
// keeps each bh's K/V pinned to one XCD's L2.
__launch_bounds__(256)
__global__ void attn_kernel(const unsigned short* __restrict__ Q,
                            const unsigned short* __restrict__ K,
                            const unsigned short* __restrict__ Vt,
                            const float* __restrict__ rel_bias,
                            unsigned short* __restrict__ ctx) {
  __shared__ __attribute__((aligned(16))) char smem[17664];
  float* brev = (float*)smem;              // 2112 f32 bias table (dead after loop)
  float* red  = (float*)smem;              // 64*68 f32 epilogue scratch (aliases brev)
  float* lred = (float*)(smem + 17408);    // 64 f32

  const int tid = threadIdx.x;
  const int w = tid >> 6, lane = tid & 63;
  const int col = lane & 15, quad = lane >> 4;
  const int bid = blockIdx.x;
  const int xcd = bid & 7, slot = bid >> 3;
  const int bh = (slot >> 5) * 8 + xcd;     // 8 bh per XCD (K/V set = 4MB = L2)
  const int qt = slot & 31;
  const int h = bh & (NHEADS - 1), b = bh >> 4;
  const unsigned short* qp = Q + (size_t)bh * S_LEN * DK;
  const f32x4 fzero = {0.f, 0.f, 0.f, 0.f};

  // windowed reversed bias table (log2e-scaled), idx = j - (q - qt*64) + 63
  const int tbase = 1985 - qt * 64;
#pragma unroll
  for (int it = 0; it < 9; it++) {
    int idx = it * 256 + tid;
    if (idx < 2112) {
      int rel = 3072 - (tbase + idx);
      rel = rel < 0 ? 0 : (rel > 2048 ? 2048 : rel);
      brev[idx] = rel_bias[rel * NHEADS + h] * 1.44269504089f;
    }
  }

  // Q as B-operand frags: qb[qs][ks], q = qt*64 + qs*16 + col
  f16x8 qb[4][2];
#pragma unroll
  for (int qs = 0; qs < 4; qs++)
#pragma unroll
    for (int ks = 0; ks < 2; ks++)
      qb[qs][ks] = frag_ld(qp + (size_t)(qt * 64 + qs * 16 + col) * DK + ks * 32 + quad * 8);

  f32x4 o[4][4];      // partial o[q=qs*16+quad*4+r][d=ds*16+col] over wave's 32 j
  float rsum[4];      // partial l[q=qs*16+col] over lane's j
#pragma unroll
  for (int qs = 0; qs < 4; qs++) {
#pragma unroll
    for (int ds = 0; ds < 4; ds++) o[qs][ds] = fzero;
    rsum[qs] = 0.f;
  }

  // per-lane fragment base inside a 32-block (2048 elems): row*32 + quad*8
  const int koff = col * 32 + quad * 8;
  const unsigned short* kptr = K + (size_t)bh * (DK * S_LEN) + w * 2048 + koff;
  const unsigned short* vptr = Vt + (size_t)bh * (DK * S_LEN) + w * 2048 + koff;
  // bias: idx = ck*128 + w*32 + jsub*16 + quad*4 + r - (qs*16 + col) + 63
  const float* bq = brev + (w * 32 + quad * 4 - col + 63);

  __syncthreads();  // brev ready

#define SB() __builtin_amdgcn_sched_barrier(0)

#define LOADK(dst, p)                                                          \
  dst[0][0] = frag_ld(p);                                                      \
  dst[0][1] = frag_ld(p + 1024);                                               \
  dst[1][0] = frag_ld(p + 512);                                                \
  dst[1][1] = frag_ld(p + 1536);

#define LOADV(dst, p)                                                          \
  _Pragma("unroll")                                                            \
  for (int ds = 0; ds < 4; ds++) dst[ds] = frag_ld(p + ds * 512);

#define COMPUTE(ka, vb)                                                        \
  {                                                                            \
    __builtin_amdgcn_s_setprio(1);                                             \
    float bb[20];                                                              \
    _Pragma("unroll")                                                          \
    for (int g = 0; g < 5; g++)                                                \
      _Pragma("unroll")                                                        \
      for (int r = 0; r < 4; r++) bb[g * 4 + r] = bq[(g - 3) * 16 + r];        \
    _Pragma("unroll")                                                          \
    for (int qs = 0; qs < 4; qs++) {                                           \
      h16x2 pk[4];                                                             \
      _Pragma("unroll")                                                        \
      for (int js = 0; js < 2; js++) {                                         \
        f32x4 bias4;                                                           \
        _Pragma("unroll")                                                      \
        for (int r = 0; r < 4; r++) bias4[r] = bb[(js - qs + 3) * 4 + r];      \
        f32x4 sc = mfma16(ka[js][1], qb[qs][1],                                \
                          mfma16(ka[js][0], qb[qs][0], bias4));                \
        float p0 = __builtin_amdgcn_exp2f(sc[0]);                              \
        float p1 = __builtin_amdgcn_exp2f(sc[1]);                              \
        float p2 = __builtin_amdgcn_exp2f(sc[2]);                              \
        float p3 = __builtin_amdgcn_exp2f(sc[3]);                              \
        rsum[qs] += (p0 + p1) + (p2 + p3);                                     \
        pk[js * 2]     = __builtin_amdgcn_cvt_pkrtz(p0, p1);                   \
        pk[js * 2 + 1] = __builtin_amdgcn_cvt_pkrtz(p2, p3);                   \
      }                                                                        \
      f16x8 pa;                                                                \
      __builtin_memcpy(&pa, pk, 16);                                           \
      _Pragma("unroll")                                                        \
      for (int ds = 0; ds < 4; ds++)                                           \
        o[qs][ds] = mfma16(pa, vb[ds], o[qs][ds]);                             \
    }                                                                          \
    __builtin_amdgcn_s_setprio(0);                                             \
  }

  f16x8 kaA[2][2], kaB[2][2], vbA[4], vbB[4];
  LOADK(kaA, kptr) LOADV(vbA, vptr) kptr += 8192; vptr += 8192;   // chunk 0
  LOADK(kaB, kptr) LOADV(vbB, vptr) kptr += 8192; vptr += 8192;   // chunk 1
  SB();
#pragma unroll 1
  for (int ck = 0; ck < 14; ck += 2) {
    COMPUTE(kaA, vbA) bq += 128;       // chunk ck       (waits vmcnt(8) auto)
    SB();
    LOADK(kaA, kptr) LOADV(vbA, vptr) kptr += 8192; vptr += 8192;  // ck+2
    SB();
    COMPUTE(kaB, vbB) bq += 128;       // chunk ck+1
    SB();
    LOADK(kaB, kptr) LOADV(vbB, vptr) kptr += 8192; vptr += 8192;  // ck+3
    SB();
  }
  COMPUTE(kaA, vbA) bq += 128;         // chunk 14
  COMPUTE(kaB, vbB)                    // chunk 15

  // finish l: sum over quads (j within wave) -> all lanes of col hold wave-partial l[q]
#pragma unroll
  for (int qs = 0; qs < 4; qs++) {
    rsum[qs] += __shfl_xor(rsum[qs], 16);
    rsum[qs] += __shfl_xor(rsum[qs], 32);
  }

  // cross-wave reduction (sequential, in-place; red stride 68 for alignment+banks)
  __syncthreads();
  for (int ws = 3; ws >= 0; ws--) {
    if (w == ws) {
#pragma unroll
      for (int qs = 0; qs < 4; qs++) {
#pragma unroll
        for (int ds = 0; ds < 4; ds++) {
#pragma unroll
          for (int r = 0; r < 4; r++) {
            int q = qs * 16 + quad * 4 + r, d = ds * 16 + col;
            if (ws == 3) red[q * 68 + d] = o[qs][ds][r];
            else         red[q * 68 + d] += o[qs][ds][r];
          }
        }
        int ql = qs * 16 + col;
        if (ws == 3) lred[ql] = rsum[qs];
        else         lred[ql] += rsum[qs];
      }
    }
    __syncthreads();
  }

  // cooperative readout: wave w handles q rows [w*16, w*16+16)
#pragma unroll
  for (int pass = 0; pass < 4; pass++) {
    int ql = w * 16 + pass * 4 + quad;
    f32x4 ov = *(const f32x4*)&red[ql * 68 + col * 4];
    float inv = 1.0f / lred[ql];
    h16x2 lo = __builtin_amdgcn_cvt_pkrtz(ov[0] * inv, ov[1] * inv);
    h16x2 hi = __builtin_amdgcn_cvt_pkrtz(ov[2] * inv, ov[3] * inv);
    uint2 pkd;
    __builtin_memcpy(&pkd.x, &lo, 4);
    __builtin_memcpy(&pkd.y, &hi, 4);
    *(uint2*)&ctx[((size_t)b * S_LEN + qt * 64 + ql) * DMODEL + h * DK + col * 4] = pkd;
  }
}

extern "C" void kernel_launch(void* const* d_in, const int* in_sizes, int n_in,
                              void* d_out, int out_size, void* d_ws, size_t ws_size,
                              hipStream_t stream) {
  (void)in_sizes; (void)n_in; (void)out_size; (void)ws_size;
  const float* x        = (const float*)d_in[0];
  const float* W_qkv    = (const float*)d_in[1];
  const float* b_qkv    = (const float*)d_in[2];
  const float* W_out    = (const float*)d_in[3];
  const float* b_out    = (const float*)d_in[4];
  const float* rel_bias = (const float*)d_in[5];
  float* out = (float*)d_out;

  char* ws = (char*)d_ws;
  unsigned short* xh     = (unsigned short*)(ws + 0);          // [8192,1024] f16 (aliases ctx)
  unsigned short* ctxh   = (unsigned short*)(ws + 0);
  unsigned short* Wqkv_t = (unsigned short*)(ws + 16777216);   // [3072,1024] f16
  unsigned short* Wout_t = (unsigned short*)(ws + 23068672);   // [1024,1024] f16
  unsigned short* Qb     = (unsigned short*)(ws + 25165824);   // [4,16,2048,64] f16
  unsigned short* Kb     = (unsigned short*)(ws + 41943040);   // [4,16,64blk,2,32,32] f16
  unsigned short* Vtb    = (unsigned short*)(ws + 58720256);   // [4,16,64blk,64,32] f16

  convert_f32_f16<<<(8192 * 1024 / 4 + 255) / 256, 256, 0, stream>>>(x, xh, 8192 * 1024 / 4);
  transpose_f32_f16<<<dim3(3072 / 32, 1024 / 32), dim3(32, 8), 0, stream>>>(W_qkv, Wqkv_t, 1024, 3072);
  transpose_f32_f16<<<dim3(1024 / 32, 1024 / 32), dim3(32, 8), 0, stream>>>(W_out, Wout_t, 1024, 1024);
  gemm_bt<<<dim3(3072 / 128, 8192 / 128), 256, 0, stream>>>(
      xh, Wqkv_t, 8192, 3072, 1024, 0, b_qkv, nullptr, Qb, Kb, Vtb);
  attn_kernel<<<4 * NHEADS * (S_LEN / 64), 256, 0, stream>>>(Qb, Kb, Vtb, rel_bias, ctxh);
  gemm_bt<<<dim3(1024 / 128, 8192 / 128), 256, 0, stream>>>(
      ctxh, Wout_t, 8192, 1024, 1024, 1, b_out, out, nullptr, nullptr, nullptr);
}